// Round 6
// baseline (205.082 us; speedup 1.0000x reference)
//
#include <hip/hip_runtime.h>
#include <cmath>

// ---------------- problem constants ----------------
#define M_ROWS   11520      // 2*5760
#define DIM      512
#define HID      1960
#define HIDP     2048       // padded HID (zeros)
#define KP2      1984       // GEMM2 K-loop bound: 31*64 >= HID, cols [1960,1984) are zero
#define OH       20
#define OW       36
#define LVEC     720        // OH*OW
#define NCH      40         // HID/49
#define BPRIME   16         // M_ROWS / LVEC

typedef unsigned short u16;
typedef __bf16 bf16x8 __attribute__((ext_vector_type(8)));
typedef float  f32x4  __attribute__((ext_vector_type(4)));
typedef unsigned short u16x8 __attribute__((ext_vector_type(8)));

__device__ __forceinline__ u16 f2bf(float f) {
    unsigned u = __float_as_uint(f);
    u += 0x7fffu + ((u >> 16) & 1u);   // RNE
    return (u16)(u >> 16);
}
__device__ __forceinline__ float bf2f(u16 h) {
    return __uint_as_float(((unsigned)h) << 16);
}

__device__ __forceinline__ void gload_lds16(const void* g, void* l) {
    __builtin_amdgcn_global_load_lds(
        (const __attribute__((address_space(1))) void*)g,
        (__attribute__((address_space(3))) void*)l, 16, 0, 0);
}

// Raw barrier with compiler memory fences (no implicit vmcnt(0) drain).
__device__ __forceinline__ void wg_barrier() {
    asm volatile("" ::: "memory");
    __builtin_amdgcn_s_barrier();
    asm volatile("" ::: "memory");
}

// ---------------- fused fp32 -> bf16 converts + g2 pad-zeroing (one dispatch) ----------------
#define CVT_XB   5760
#define CVT_W1B  1024
#define CVT_W2B  1024
#define CVT_Z    270       // 11520 rows * 24 cols / (256*4)
__global__ __launch_bounds__(256) void cvt_all(const float* __restrict__ x,
                                               const float* __restrict__ W1,
                                               const float* __restrict__ W2,
                                               u16* __restrict__ xb,
                                               u16* __restrict__ W1b,
                                               u16* __restrict__ W2b,
                                               u16* __restrict__ g2) {
    const int b = blockIdx.x;
    const int tid = threadIdx.x;
    ushort4 o;
    if (b < CVT_XB) {
        int i = (b * 256 + tid) * 4;
        float4 v = *(const float4*)(x + i);
        o.x = f2bf(v.x); o.y = f2bf(v.y); o.z = f2bf(v.z); o.w = f2bf(v.w);
        *(ushort4*)(xb + i) = o;
    } else if (b < CVT_XB + CVT_W1B) {
        int i = ((b - CVT_XB) * 256 + tid) * 4;      // over 2048*512
        if (i < HID * DIM) {
            float4 v = *(const float4*)(W1 + i);
            o.x = f2bf(v.x); o.y = f2bf(v.y); o.z = f2bf(v.z); o.w = f2bf(v.w);
        } else {
            o.x = o.y = o.z = o.w = 0;
        }
        *(ushort4*)(W1b + i) = o;
    } else if (b < CVT_XB + CVT_W1B + CVT_W2B) {
        int i = ((b - CVT_XB - CVT_W1B) * 256 + tid) * 4;   // over 512*2048
        int d = i / HIDP, c = i - d * HIDP;
        if (c < HID) {
            float4 v = *(const float4*)(W2 + (size_t)d * HID + c);
            o.x = f2bf(v.x); o.y = f2bf(v.y); o.z = f2bf(v.z); o.w = f2bf(v.w);
        } else {
            o.x = o.y = o.z = o.w = 0;
        }
        *(ushort4*)(W2b + i) = o;
    } else {
        int i = ((b - CVT_XB - CVT_W1B - CVT_W2B) * 256 + tid) * 4;  // over 11520*24
        int row = i / 24, c = i - row * 24;
        o.x = o.y = o.z = o.w = 0;
        *(ushort4*)(g2 + (size_t)row * HIDP + HID + c) = o;
    }
}

// ---------------- GEMM1: 8-phase-style pipelined NT-GEMM (counted vmcnt) ----------------
// h = x @ W1^T + b1 -> bf16.  M=11520, K=512, N=2048.
// Tile 256(M) x 128(N), BK=64, NT=8 K-tiles.  512 thr = 8 waves (2M x 4N),
// wave tile 128x32 (acc[8][2]).  2 K-tile LDS buffers (96 KB, 1 block/CU).
//
// Per K-tile T (buf b=T&1), 4 quadrant phases q=0..3; phase q:
//   ds_read A-frags m={2q,2q+1} (4x b128); q0 also reads all B-frags (4x b128)
//   stage (2x global_load_lds, 64-row chunks):
//     q0: A(T+1) rows{64-127,192-255} -> buf 1-b   (A(T-1).hi dead after prev q3)
//     q1: B(T+2) rows{0-63,64-127}    -> buf b     (B(T) dead after q0)
//     q2: A(T+2) rows{0-63,128-191}   -> buf b     (A(T).lo dead after q1: quadrant
//                                                   q reads wave-local rows [32q,32q+32))
//   barrier;  setprio(1); 8 MFMA; setprio(0);
//   q3: s_waitcnt vmcnt(4)  (NEVER 0 in main loop);  barrier
// Coverage (per-wave FIFO): at vmcnt(4)@T.q3 the 4 newest loads are
// {B(T+2), A(T+2).lo}; everything older (incl. A(T+1).hi staged @T.q0, and all
// of K-tile T+1 staged during T-1) has landed; the trailing barrier publishes.
// Region freshness: every stage target verified dead-by-barrier (see notes).
// Epilogue: LDS-bounce (stride 136) -> coalesced 16B stores.
__global__ __launch_bounds__(512, 2) void gemm1_8p(const u16* __restrict__ A,
                                                   const u16* __restrict__ B,
                                                   const float* __restrict__ bias,
                                                   u16* __restrict__ C) {
    constexpr int BUFU = (256 + 128) * 64;   // u16 per buffer (A then B)
    constexpr int NT   = DIM / 64;           // 8
    __shared__ u16 smem[2 * BUFU];           // 96 KB

    const int tid  = threadIdx.x;
    const int NB   = gridDim.x;              // 720, %8==0
    const int v    = (blockIdx.x & 7) * (NB >> 3) + (blockIdx.x >> 3);
    const int bm   = v >> 4;                 // ntn = 16
    const int bn   = v & 15;
    const int lane = tid & 63;
    const int wv   = tid >> 6;               // 0..7
    const int wr   = wv >> 2;                // 0..1  (M)
    const int wc   = wv & 3;                 // 0..3  (N)
    const int r    = lane & 15;
    const int quad = lane >> 4;

    const size_t Arow0 = (size_t)bm * 256;
    const size_t Brow0 = (size_t)bn * 128;

    // stage one 64-row x 64-col chunk (512 x 16B = 1 load/thread)
    const int srl = tid >> 3;                // 0..63 row within chunk
    const int scp = tid & 7;
    auto stA = [&](int b2, int kt, int R0) {
        int rl = R0 + srl;
        int cg = scp ^ (rl & 7);
        gload_lds16(A + (Arow0 + rl) * DIM + kt + cg * 8,
                    (char*)(smem + b2 * BUFU) + R0 * 128 + tid * 16);
    };
    auto stB = [&](int b2, int kt, int R0) {
        int rl = R0 + srl;
        int cg = scp ^ (rl & 7);
        gload_lds16(B + (Brow0 + rl) * DIM + kt + cg * 8,
                    (char*)(smem + b2 * BUFU + 256 * 64) + R0 * 128 + tid * 16);
    };

    // prologue: K-tile 0 complete + B(1) + A(1).lo  (10 loads/thread)
    stB(0,  0, 0);  stB(0,  0, 64);      // B(0)
    stA(0,  0, 0);  stA(0,  0, 128);     // A(0).lo
    stA(0,  0, 64); stA(0,  0, 192);     // A(0).hi
    stB(1, 64, 0);  stB(1, 64, 64);      // B(1)
    stA(1, 64, 0);  stA(1, 64, 128);     // A(1).lo
    asm volatile("s_waitcnt vmcnt(4)" ::: "memory");   // K-tile 0 landed
    wg_barrier();

    f32x4 acc[8][2] = {};
    bf16x8 bg[2][2];

    for (int T = 0; T < NT; ++T) {
        const int b = T & 1;
        const u16* sAb = smem + b * BUFU;
        const u16* sBb = sAb + 256 * 64;
#pragma unroll
        for (int q = 0; q < 4; ++q) {
            bf16x8 af[2][2];
#pragma unroll
            for (int m2 = 0; m2 < 2; m2++) {
                int row = wr * 128 + (2 * q + m2) * 16 + r;
#pragma unroll
                for (int kk = 0; kk < 2; kk++) {
                    int c = (kk * 4 + quad) ^ (row & 7);
                    af[m2][kk] = *(const bf16x8*)(sAb + row * 64 + c * 8);
                }
            }
            if (q == 0) {
#pragma unroll
                for (int n = 0; n < 2; n++) {
                    int row = wc * 32 + n * 16 + r;
#pragma unroll
                    for (int kk = 0; kk < 2; kk++) {
                        int c = (kk * 4 + quad) ^ (row & 7);
                        bg[n][kk] = *(const bf16x8*)(sBb + row * 64 + c * 8);
                    }
                }
                if (T + 1 < NT) { stA(1 - b, (T + 1) * 64, 64); stA(1 - b, (T + 1) * 64, 192); }
            } else if (q == 1) {
                if (T + 2 < NT) { stB(b, (T + 2) * 64, 0); stB(b, (T + 2) * 64, 64); }
            } else if (q == 2) {
                if (T + 2 < NT) { stA(b, (T + 2) * 64, 0); stA(b, (T + 2) * 64, 128); }
            }
            wg_barrier();                      // phase-aligned: stages issued
            __builtin_amdgcn_s_setprio(1);
#pragma unroll
            for (int m2 = 0; m2 < 2; m2++)
#pragma unroll
                for (int n = 0; n < 2; n++)
#pragma unroll
                    for (int kk = 0; kk < 2; kk++)
                        acc[2 * q + m2][n] = __builtin_amdgcn_mfma_f32_16x16x32_bf16(
                            af[m2][kk], bg[n][kk], acc[2 * q + m2][n], 0, 0, 0);
            __builtin_amdgcn_s_setprio(0);
            if (q == 3) {
                if (T + 2 < NT)      asm volatile("s_waitcnt vmcnt(4)" ::: "memory");
                else if (T + 1 < NT) asm volatile("s_waitcnt vmcnt(0)" ::: "memory");
            }
            wg_barrier();                      // publish staged tile / free regions
        }
    }

    // epilogue: bounce C-tile (256x128, stride 136) -> 16B coalesced stores
    const int gn0 = bn * 128;
#pragma unroll
    for (int n = 0; n < 2; n++) {
        int gnl = wc * 32 + n * 16 + r;
        int gng = gn0 + gnl;
        float bv = (gng < HID) ? bias[gng] : 0.0f;
#pragma unroll
        for (int m = 0; m < 8; m++) {
            int gml = wr * 128 + m * 16 + quad * 4;
#pragma unroll
            for (int qq = 0; qq < 4; qq++)
                smem[(gml + qq) * 136 + gnl] = f2bf(acc[m][n][qq] + bv);
        }
    }
    asm volatile("s_waitcnt lgkmcnt(0)" ::: "memory");
    wg_barrier();
    const int row  = tid >> 1;               // 0..255
    const int half = tid & 1;
    const u16* src = smem + row * 136 + half * 64;
    u16* dst = C + (size_t)(bm * 256 + row) * HIDP + gn0 + half * 64;
#pragma unroll
    for (int j = 0; j < 8; j++)
        *(u16x8*)(dst + j * 8) = *(const u16x8*)(src + j * 8);
}

// ---------------- GEMM2: round-1 proven 2-barrier kernel (control) ----------------
// out = g2 @ W2^T + b2 -> fp32.  128x64 tile, BK=64, 8 waves (4M x 2N) of
// 32x32, K trimmed to 1984 (g2 cols [1960,1984) zeroed by cvt_all).
__global__ __launch_bounds__(512) void gemm2_bt(const u16* __restrict__ A,
                                                const u16* __restrict__ B,
                                                const float* __restrict__ bias,
                                                float* __restrict__ C) {
    __shared__ u16 sA[128 * 64];
    __shared__ u16 sB[64 * 64];

    const int tid  = threadIdx.x;
    const int NB   = gridDim.x;          // 720, %8==0
    const int v    = (blockIdx.x & 7) * (NB >> 3) + (blockIdx.x >> 3);
    const int bm   = v >> 3;             // ntn = 8
    const int bn   = v & 7;
    const int lane = tid & 63;
    const int wv   = tid >> 6;
    const int wm   = (wv >> 1) * 32;
    const int wn   = (wv & 1) * 32;
    const int r    = lane & 15;
    const int quad = lane >> 4;

    const size_t Arow0 = (size_t)bm * 128 * HIDP;
    const size_t Brow0 = (size_t)bn * 64 * HIDP;

    f32x4 acc[2][2] = {};

    for (int kt = 0; kt < KP2; kt += 64) {
        __syncthreads();
#pragma unroll
        for (int i = 0; i < 2; i++) {    // A: 1024 chunks / 512 threads
            int e   = i * 512 + tid;
            int row = e >> 3;
            int cg  = (e & 7) ^ (row & 7);
            gload_lds16(A + Arow0 + (size_t)row * HIDP + kt + cg * 8, (char*)sA + e * 16);
        }
        {                                // B: 512 chunks / 512 threads
            int row = tid >> 3;
            int cg  = (tid & 7) ^ (row & 7);
            gload_lds16(B + Brow0 + (size_t)row * HIDP + kt + cg * 8, (char*)sB + tid * 16);
        }
        __syncthreads();
#pragma unroll
        for (int kk = 0; kk < 2; kk++) {
            bf16x8 af[2], bg[2];
#pragma unroll
            for (int m = 0; m < 2; m++) {
                int row = wm + m * 16 + r;
                int c   = (kk * 4 + quad) ^ (row & 7);
                af[m] = *(const bf16x8*)(sA + row * 64 + c * 8);
            }
#pragma unroll
            for (int u = 0; u < 2; u++) {
                int row = wn + u * 16 + r;
                int c   = (kk * 4 + quad) ^ (row & 7);
                bg[u] = *(const bf16x8*)(sB + row * 64 + c * 8);
            }
#pragma unroll
            for (int m = 0; m < 2; m++)
#pragma unroll
                for (int u = 0; u < 2; u++)
                    acc[m][u] = __builtin_amdgcn_mfma_f32_16x16x32_bf16(
                        af[m], bg[u], acc[m][u], 0, 0, 0);
        }
    }

    const int gm0 = bm * 128 + wm;
    const int gn0 = bn * 64 + wn;
#pragma unroll
    for (int u = 0; u < 2; u++) {
        int gn = gn0 + u * 16 + r;
        float bv = bias[gn];
#pragma unroll
        for (int m = 0; m < 2; m++) {
            int gm = gm0 + m * 16 + quad * 4;
#pragma unroll
            for (int q = 0; q < 4; q++)
                C[(size_t)(gm + q) * DIM + gn] = acc[m][u][q] + bv;
        }
    }
}

// ---------------- mid: fold + normalize + crop + GELU + unfold, fully fused ----------------
// (round-1 version, unchanged)
__global__ __launch_bounds__(512) void mid_fused(const u16* __restrict__ hg,
                                                 u16* __restrict__ g2) {
    __shared__ u16 sh[12 * 20 * 56];   // 13440 u16 = 26880 B
    __shared__ u16 sG[34 * 58];        //  1972 u16 =  3944 B

    const int b   = blockIdx.x;
    const int bp  = b / (NCH * 4);
    const int rr  = b - bp * (NCH * 4);
    const int ch  = rr >> 2;
    const int s   = (rr >> 1) & 1;
    const int xh  = rr & 1;
    const int o0  = s * 10;            // first owned oy
    const int lo  = s * 8;             // first loaded oy
    const int ox0 = xh * 16;           // first loaded ox
    const int n0  = bp * LVEC;
    const int c0  = ch * 49;
    const int c0f = c0 & ~7;           // 16B-aligned channel base
    const int koff = c0 & 7;           // 0..7 (koff + 49 <= 56)
    const int tid = threadIdx.x;

    // phase 0: 12 oy-rows x 20 ox-cols x 7 chunks of 16B, DMA'd to LDS.
    {
        const char* hb = (const char*)(hg + (size_t)(n0 + lo * 36 + ox0) * HIDP + c0f);
        for (int t = tid; t < 12 * 20 * 7; t += 512) {
            int r   = (int)(((unsigned)t * 74899u) >> 19);
            int c   = t - r * 7;
            int loy = (int)(((unsigned)r * 3277u) >> 16);
            int oxl = r - 20 * loy;
            gload_lds16(hb + (size_t)(loy * 36 + oxl) * (HIDP * 2) + c * 16,
                        (char*)sh + t * 16);
        }
    }
    __syncthreads();

    // phase 1: G rows [3*o0, 3*o0+34) x local px [0,58) -> sG
    const int pxl = tid & 63;
    const int rg  = tid >> 6;          // 0..7, wave-uniform
    if (pxl < 58) {
        const int  pxg  = pxl + 54 * xh;              // global px
        const bool pxin = (pxg >= 3) && (pxg <= 110);
        const int  kx0  = pxg % 3;
        int  ct[3];
        bool vx[3];
        int  cx = 0;
#pragma unroll
        for (int dx = 0; dx < 3; dx++) {
            int kx = kx0 + 3 * dx, rx = pxg - kx;
            bool ok = pxin && (kx <= 6) && (rx >= 0) && (rx <= 105);
            vx[dx] = ok;
            ct[dx] = ok ? ((rx / 3) - ox0) * 56 + kx : 0;
            cx += ok ? 1 : 0;
        }
        const float fcx = (cx == 3) ? (1.0f / 3.0f) : ((cx == 2) ? 0.5f : 1.0f);

        for (int pr = rg; pr < 34; pr += 8) {
            int py = 3 * o0 + pr;      // wave-uniform
            float val = 0.0f;
            if (pxin && py >= 3 && py <= 62) {
                int ky0 = py % 3;
                float sum = 0.0f;
                int cy = 0;
#pragma unroll
                for (int dy = 0; dy < 3; dy++) {
                    int ky = ky0 + 3 * dy, ry = py - ky;   // uniform
                    if (ky <= 6 && ry >= 0 && ry <= 57) {  // uniform branch
                        int rt = (ry / 3 - lo) * (20 * 56) + ky * 7 + koff;
                        cy++;
                        float v0 = bf2f(sh[rt + ct[0]]);
                        float v1 = bf2f(sh[rt + ct[1]]);
                        float v2 = bf2f(sh[rt + ct[2]]);
                        sum += vx[0] ? v0 : 0.0f;
                        sum += vx[1] ? v1 : 0.0f;
                        sum += vx[2] ? v2 : 0.0f;
                    }
                }
                float fcy = (cy == 3) ? (1.0f / 3.0f) : ((cy == 2) ? 0.5f : 1.0f);
                float m = sum * fcx * fcy;
                val = 0.5f * m * (1.0f + erff(m * 0.70710678118654752f));  // exact gelu
            }
            sG[pr * 58 + pxl] = f2bf(val);
        }
    }
    __syncthreads();

    // phase 2: unfold sG -> g2 (magic-mul indices, no LUTs)
    {
        u16* g2row = g2 + (size_t)(n0 + o0 * 36 + 18 * xh) * HIDP + c0;
        for (int j = tid; j < 10 * 18 * 49; j += 512) {
            int l2 = (int)(((unsigned)j * 42800u) >> 21);
            int k  = j - l2 * 49;
            int oy = (int)(((unsigned)l2 * 57u) >> 10);
            int ox = l2 - 18 * oy;
            int ky = (int)(((unsigned)k * 37u) >> 8);
            int kx = k - 7 * ky;
            g2row[(size_t)(oy * 36 + ox) * HIDP + k] =
                sG[(3 * oy + ky) * 58 + 3 * ox + kx];
        }
    }
}

// ---------------- launch ----------------
extern "C" void kernel_launch(void* const* d_in, const int* in_sizes, int n_in,
                              void* d_out, int out_size, void* d_ws, size_t ws_size,
                              hipStream_t stream) {
    (void)in_sizes; (void)n_in; (void)out_size; (void)ws_size;
    const float* x  = (const float*)d_in[0];
    const float* W1 = (const float*)d_in[1];
    const float* b1 = (const float*)d_in[2];
    const float* W2 = (const float*)d_in[3];
    const float* b2 = (const float*)d_in[4];
    float* out = (float*)d_out;

    char* ws = (char*)d_ws;
    u16* xb  = (u16*)(ws);                       // 11520*512*2  = 11,796,480
    u16* W1b = (u16*)(ws + 11796480);            // 2048*512*2   =  2,097,152
    u16* W2b = (u16*)(ws + 13893632);            // 512*2048*2   =  2,097,152
    u16* hg  = (u16*)(ws + 15990784);            // 11520*2048*2 = 47,185,920
    u16* g2  = (u16*)(ws + 63176704);            // 11520*2048*2 = 47,185,920 (total 110 MB)

    // converts + g2 pad-zeroing (single dispatch)
    cvt_all<<<CVT_XB + CVT_W1B + CVT_W2B + CVT_Z, 256, 0, stream>>>(
        x, W1, W2, xb, W1b, W2b, g2);

    // GEMM1: 8-phase pipelined 256x128 tiles, grid 45*16 = 720, 96 KB LDS
    gemm1_8p<<<(M_ROWS / 256) * (HIDP / 128), 512, 0, stream>>>(xb, W1b, b1, hg);

    // middle: fold/normalize/gelu/unfold fused, hg -> g2 (G stays in LDS)
    mid_fused<<<BPRIME * NCH * 4, 512, 0, stream>>>(hg, g2);

    // GEMM2: round-1 2-barrier 128x64 tiles, grid 90*8 = 720
    gemm2_bt<<<(M_ROWS / 128) * (DIM / 64), 512, 0, stream>>>(g2, W2b, b2, out);
}